// Round 3
// baseline (530.278 us; speedup 1.0000x reference)
//
#include <hip/hip_runtime.h>
#include <math.h>

typedef unsigned int u32;
typedef unsigned short u16;
typedef __attribute__((ext_vector_type(8))) short bf16x8;   // 8 bf16 in 4 VGPRs
typedef __attribute__((ext_vector_type(4))) float f32x4;

__device__ inline u16 f2bf(float x) {  // round-to-nearest-even
    union { float f; u32 u; } v; v.f = x;
    u32 r = v.u + 0x7FFFu + ((v.u >> 16) & 1u);
    return (u16)(r >> 16);
}
__device__ inline float4 bf4_to_f4(uint2 p) {
    float4 r;
    r.x = __uint_as_float(p.x << 16);
    r.y = __uint_as_float(p.x & 0xffff0000u);
    r.z = __uint_as_float(p.y << 16);
    r.w = __uint_as_float(p.y & 0xffff0000u);
    return r;
}

// ---------------------------------------------------------------------------
// Clifford GNN message passing, restructured:
//   agg[n] = sum_e w_e*(h[src] .* r[rel]),  w_e = gate(rel)*norm(e)
//   t = ML(agg) + h + msg_b*wsum ;  out = UL(t) + upd_b  (channel-major store)
// agg is computed INSIDE the GEMM kernel (per-block, straight into LDS bf16),
// so the intermediate never touches HBM. Gathers use a bf16 copy of h when
// workspace allows (halves gather traffic, table fits L3).
// ---------------------------------------------------------------------------

// Build Clifford kernel matrices Kb[j][k] = K[j][k] in bf16 (k contiguous).
__global__ void build_mats_kernel(const float* __restrict__ msg_w,
                                  const float* __restrict__ upd_w,
                                  u16* __restrict__ Kbm, u16* __restrict__ Kbu) {
    const int   s_tab[16] = {0,1,2,3, 1,0,3,2, 2,3,0,1, 3,2,1,0};
    const float g_tab[16] = {1.f,1.f,1.f,-1.f, 1.f,1.f,-1.f,1.f,
                             1.f,1.f,1.f,-1.f, 1.f,1.f,1.f,1.f};
    int idx = blockIdx.x * 256 + threadIdx.x;   // idx = j*256 + i
    int j = idx >> 8, i = idx & 255;
    int ob = j >> 6, oc = j & 63, ib = i >> 6, ic = i & 63;
    int t = ob * 4 + ib;
    int widx = s_tab[t] * 4096 + oc * 64 + ic;  // w[s][oc][ic]
    float sg = g_tab[t];
    Kbm[idx] = f2bf(sg * msg_w[widx]);
    Kbu[idx] = f2bf(sg * upd_w[widx]);
}

// gate[r] = sigmoid( sum_j rel_emb[r, j] * gate_w[(j&63)*4 + (j>>6)] + gate_b )
__global__ void gate_kernel(const float* __restrict__ rel_emb,
                            const float* __restrict__ gate_w,
                            const float* __restrict__ gate_b,
                            float* __restrict__ gate, int R) {
    int wv = threadIdx.x >> 6, lane = threadIdx.x & 63;
    int r = blockIdx.x * 4 + wv;
    if (r >= R) return;
    float4 rv = *(const float4*)(rel_emb + (size_t)r * 256 + lane * 4);
    float s = 0.f;
    float rvv[4] = {rv.x, rv.y, rv.z, rv.w};
#pragma unroll
    for (int c = 0; c < 4; ++c) {
        int j = lane * 4 + c;
        s += rvv[c] * gate_w[(j & 63) * 4 + (j >> 6)];
    }
#pragma unroll
    for (int d = 32; d > 0; d >>= 1) s += __shfl_down(s, d);
    if (lane == 0) gate[r] = 1.0f / (1.0f + expf(-(s + gate_b[0])));
}

__global__ void degree_kernel(const int* __restrict__ ei, int E,
                              u32* __restrict__ deg_src, u32* __restrict__ deg_dst) {
    int e = blockIdx.x * 256 + threadIdx.x;
    if (e >= E) return;
    atomicAdd(&deg_src[ei[e]], 1u);
    atomicAdd(&deg_dst[ei[E + e]], 1u);
}

// Single-block exclusive scan of deg_dst -> offs and cursor (8 elems/thread).
__global__ void scan_kernel(const u32* __restrict__ deg, u32* __restrict__ offs,
                            u32* __restrict__ cursor, int N) {
    __shared__ u32 wtot[16];
    __shared__ u32 wpre[17];
    __shared__ u32 running;
    int t = threadIdx.x, lane = t & 63, wv = t >> 6;
    if (t == 0) running = 0u;
    __syncthreads();
    for (int base = 0; base < N; base += 8192) {
        int i0 = base + t * 8;
        u32 v[8]; u32 s = 0;
#pragma unroll
        for (int c = 0; c < 8; ++c) { v[c] = (i0 + c < N) ? deg[i0 + c] : 0u; s += v[c]; }
        u32 sc = s;
#pragma unroll
        for (int d = 1; d < 64; d <<= 1) { u32 o = __shfl_up(sc, d); if (lane >= d) sc += o; }
        if (lane == 63) wtot[wv] = sc;
        __syncthreads();
        if (t < 16) {
            u32 x = wtot[t], xs2 = x;
#pragma unroll
            for (int d = 1; d < 16; d <<= 1) { u32 o = __shfl_up(xs2, d); if (t >= d) xs2 += o; }
            wpre[t] = xs2 - x;
            if (t == 15) wpre[16] = xs2;   // chunk total
        }
        __syncthreads();
        u32 excl = running + wpre[wv] + (sc - s);
#pragma unroll
        for (int c = 0; c < 8; ++c) {
            if (i0 + c < N) { offs[i0 + c] = excl; cursor[i0 + c] = excl; }
            excl += v[c];
        }
        __syncthreads();
        if (t == 0) running += wpre[16];
        __syncthreads();
    }
}

// Bucket-fill with precomputed per-edge weight: ids[pos]={src,rel}, wbuf[pos]=w.
__global__ void fill_kernel(const int* __restrict__ ei, const int* __restrict__ et,
                            const u32* __restrict__ deg_src,
                            const u32* __restrict__ deg_dst,
                            const float* __restrict__ gate,
                            u32* __restrict__ cursor,
                            uint2* __restrict__ ids, float* __restrict__ wbuf, int E) {
    int e = blockIdx.x * 256 + threadIdx.x;
    if (e >= E) return;
    int src = ei[e];
    int dst = ei[E + e];
    int rel = et[e];
    float ds = (float)deg_src[src];
    float dd = (float)deg_dst[dst];
    float w = gate[rel] * rsqrtf(fmaxf(ds * dd, 1.0f));
    u32 pos = atomicAdd(&cursor[dst], 1u);
    ids[pos] = make_uint2((u32)src, (u32)rel);
    wbuf[pos] = w;
}

// fp32 -> bf16 bulk convert (8 elems/thread, grid-stride).
__global__ void tobf_kernel(const float* __restrict__ src, u16* __restrict__ dst, int n8) {
    for (int i = blockIdx.x * 256 + threadIdx.x; i < n8; i += gridDim.x * 256) {
        const float* p = src + (size_t)i * 8;
        float4 a = *(const float4*)(p);
        float4 b = *(const float4*)(p + 4);
        u16 tmp[8] = {f2bf(a.x), f2bf(a.y), f2bf(a.z), f2bf(a.w),
                      f2bf(b.x), f2bf(b.y), f2bf(b.z), f2bf(b.w)};
        *(uint4*)(dst + (size_t)i * 8) = *(const uint4*)tmp;
    }
}

// Fused aggregate + double GEMM. Per block: 32 node rows; 4 waves, 8 rows/wave.
// Gather phase: wave accumulates agg row in registers, writes bf16 into
// XOR-swizzled LDS: element (m,k) at ushort index m*256 + (k ^ ((m&7)<<3)).
// Phase A: t = agg @ Km^T + h + msg_b*wsum (fp32 epilogue, re-round to LDS).
// Phase B: y = t @ Ku^T + upd_b -> permuted channel-major store.
template <int BF>
__global__ __launch_bounds__(256) void fused_kernel(
    float* __restrict__ dio,
    const u16* __restrict__ Kbm, const u16* __restrict__ Kbu,
    const float* __restrict__ h, const u16* __restrict__ h_bf,
    const float* __restrict__ rel_emb, const u16* __restrict__ rel_bf,
    const u32* __restrict__ offs, const u32* __restrict__ deg_dst,
    const uint2* __restrict__ ids, const float* __restrict__ wbuf,
    const float* __restrict__ msg_b, const float* __restrict__ upd_b,
    int N) {
    __shared__ __align__(16) u16 xs[32 * 256];  // 16 KiB bf16 tile
    __shared__ float ws_l[32];                  // per-row weight sums
    const int tid = threadIdx.x;
    const int lane = tid & 63;
    const int wv = tid >> 6;        // wave owns output cols [wv*64, wv*64+64)
    const int l15 = lane & 15;
    const int kg = lane >> 4;       // k-group 0..3
    const int m0 = blockIdx.x * 32;
    const int jbase = wv * 64;

    // ---- gather/aggregate phase: 8 rows per wave ----
#pragma unroll
    for (int i = 0; i < 8; ++i) {
        int m = wv * 8 + i;
        int n = m0 + m;
        float4 acc = make_float4(0.f, 0.f, 0.f, 0.f);
        float wsum = 0.f;
        if (n < N) {
            u32 off = offs[n];
            u32 dd = deg_dst[n];
            for (u32 e = 0; e < dd; ++e) {
                uint2 id = ids[off + e];
                float w = wbuf[off + e];
                float4 hv, rv;
                if (BF) {
                    hv = bf4_to_f4(*(const uint2*)(h_bf + (size_t)id.x * 256 + lane * 4));
                    rv = bf4_to_f4(*(const uint2*)(rel_bf + (size_t)id.y * 256 + lane * 4));
                } else {
                    hv = *(const float4*)(h + (size_t)id.x * 256 + lane * 4);
                    rv = *(const float4*)(rel_emb + (size_t)id.y * 256 + lane * 4);
                }
                acc.x += w * hv.x * rv.x;
                acc.y += w * hv.y * rv.y;
                acc.z += w * hv.z * rv.z;
                acc.w += w * hv.w * rv.w;
                wsum += w;
            }
        }
        u32 lo = (u32)f2bf(acc.x) | ((u32)f2bf(acc.y) << 16);
        u32 hi = (u32)f2bf(acc.z) | ((u32)f2bf(acc.w) << 16);
        *(uint2*)&xs[m * 256 + ((lane * 4) ^ ((m & 7) << 3))] = make_uint2(lo, hi);
        if (lane == 0) ws_l[m] = wsum;
    }
    __syncthreads();

    f32x4 acc[2][4];

    // ================= phase A: acc = agg @ Km^T =================
#pragma unroll
    for (int mf = 0; mf < 2; ++mf)
#pragma unroll
        for (int nf = 0; nf < 4; ++nf) acc[mf][nf] = (f32x4)(0.f);

#pragma unroll
    for (int k0 = 0; k0 < 256; k0 += 32) {
        int kk = k0 + kg * 8;
        int ma = l15, mb = 16 + l15;
        bf16x8 a0 = *(const bf16x8*)&xs[ma * 256 + (kk ^ ((ma & 7) << 3))];
        bf16x8 a1 = *(const bf16x8*)&xs[mb * 256 + (kk ^ ((mb & 7) << 3))];
#pragma unroll
        for (int nf = 0; nf < 4; ++nf) {
            int j = jbase + nf * 16 + l15;
            bf16x8 b = *(const bf16x8*)(Kbm + (size_t)j * 256 + kk);
            acc[0][nf] = __builtin_amdgcn_mfma_f32_16x16x32_bf16(a0, b, acc[0][nf], 0, 0, 0);
            acc[1][nf] = __builtin_amdgcn_mfma_f32_16x16x32_bf16(a1, b, acc[1][nf], 0, 0, 0);
        }
    }
    __syncthreads();   // all phase-A reads of xs done before overwrite

    // ---- epilogue A: t = acc + h + msg_b*wsum ; t -> bf16 swizzled LDS ----
    float bjA[4];
#pragma unroll
    for (int nf = 0; nf < 4; ++nf) bjA[nf] = msg_b[jbase + nf * 16 + l15];
#pragma unroll
    for (int mf = 0; mf < 2; ++mf) {
#pragma unroll
        for (int r = 0; r < 4; ++r) {
            int m = mf * 16 + kg * 4 + r;             // D-frag row
            int row = m0 + m;
            if (row >= N) continue;
            float ws = ws_l[m];
            const float* hrow = h + (size_t)row * 256;
#pragma unroll
            for (int nf = 0; nf < 4; ++nf) {
                int j = jbase + nf * 16 + l15;        // D-frag col
                float t = acc[mf][nf][r] + hrow[j] + bjA[nf] * ws;
                xs[m * 256 + (j ^ ((m & 7) << 3))] = f2bf(t);
            }
        }
    }
    __syncthreads();

    // ================= phase B: acc = t @ Ku^T =================
#pragma unroll
    for (int mf = 0; mf < 2; ++mf)
#pragma unroll
        for (int nf = 0; nf < 4; ++nf) acc[mf][nf] = (f32x4)(0.f);

#pragma unroll
    for (int k0 = 0; k0 < 256; k0 += 32) {
        int kk = k0 + kg * 8;
        int ma = l15, mb = 16 + l15;
        bf16x8 a0 = *(const bf16x8*)&xs[ma * 256 + (kk ^ ((ma & 7) << 3))];
        bf16x8 a1 = *(const bf16x8*)&xs[mb * 256 + (kk ^ ((mb & 7) << 3))];
#pragma unroll
        for (int nf = 0; nf < 4; ++nf) {
            int j = jbase + nf * 16 + l15;
            bf16x8 b = *(const bf16x8*)(Kbu + (size_t)j * 256 + kk);
            acc[0][nf] = __builtin_amdgcn_mfma_f32_16x16x32_bf16(a0, b, acc[0][nf], 0, 0, 0);
            acc[1][nf] = __builtin_amdgcn_mfma_f32_16x16x32_bf16(a1, b, acc[1][nf], 0, 0, 0);
        }
    }

    // ---- epilogue B: y = acc + upd_b[j]; permuted (channel-major) store ----
#pragma unroll
    for (int nf = 0; nf < 4; ++nf) {
        int j = jbase + nf * 16 + l15;
        float bj = upd_b[j];
        int colout = (j & 63) * 4 + wv;               // j>>6 == wv for this wave
#pragma unroll
        for (int mf = 0; mf < 2; ++mf) {
#pragma unroll
            for (int r = 0; r < 4; ++r) {
                int row = m0 + mf * 16 + kg * 4 + r;
                if (row < N) dio[(size_t)row * 256 + colout] = acc[mf][nf][r] + bj;
            }
        }
    }
}

static inline size_t align4(size_t x) { return (x + 3) & ~(size_t)3; }

extern "C" void kernel_launch(void* const* d_in, const int* in_sizes, int n_in,
                              void* d_out, int out_size, void* d_ws, size_t ws_size,
                              hipStream_t stream) {
    const float* h       = (const float*)d_in[0];
    const int*   ei      = (const int*)d_in[1];   // (2,E) row-major
    const int*   et      = (const int*)d_in[2];
    const float* rel_emb = (const float*)d_in[3];
    const float* msg_w   = (const float*)d_in[4];
    const float* msg_b   = (const float*)d_in[5];
    const float* upd_w   = (const float*)d_in[6];
    const float* upd_b   = (const float*)d_in[7];
    const float* gate_w  = (const float*)d_in[8];
    const float* gate_b  = (const float*)d_in[9];

    const int N = in_sizes[0] / 256;
    const int E = in_sizes[2];
    const int R = in_sizes[3] / 256;

    // workspace layout (u32 units)
    u32* ws = (u32*)d_ws;
    size_t o = 0;
    u32* deg_src  = ws + o; o += align4((size_t)N);
    u32* deg_dst  = ws + o; o += align4((size_t)N);
    u32* offs     = ws + o; o += align4((size_t)N);
    u32* cursor   = ws + o; o += align4((size_t)N);
    uint2* ids    = (uint2*)(ws + o); o += (size_t)2 * E;
    float* wbuf   = (float*)(ws + o); o += align4((size_t)E);
    float* gate   = (float*)(ws + o); o += align4((size_t)R);
    u16* Kbm      = (u16*)(ws + o); o += 32768;  // 256*256 bf16
    u16* Kbu      = (u16*)(ws + o); o += 32768;
    size_t need_base = o;
    u16* h_bf     = (u16*)(ws + o); o += (size_t)N * 128;
    u16* rel_bf   = (u16*)(ws + o); o += (size_t)R * 128;
    size_t need_bf = o;

    if (ws_size < need_base * 4) return;  // insufficient scratch -> fail loudly
    const bool use_bf = (ws_size >= need_bf * 4);

    float* out = (float*)d_out;

    // zero degree counters (deg_src & deg_dst are adjacent)
    hipMemsetAsync(deg_src, 0, (size_t)2 * align4((size_t)N) * 4, stream);

    build_mats_kernel<<<256, 256, 0, stream>>>(msg_w, upd_w, Kbm, Kbu);
    gate_kernel<<<(R + 3) / 4, 256, 0, stream>>>(rel_emb, gate_w, gate_b, gate, R);
    degree_kernel<<<(E + 255) / 256, 256, 0, stream>>>(ei, E, deg_src, deg_dst);
    scan_kernel<<<1, 1024, 0, stream>>>(deg_dst, offs, cursor, N);
    if (use_bf) {
        tobf_kernel<<<1024, 256, 0, stream>>>(h, h_bf, N * 32);       // N*256/8
        tobf_kernel<<<64, 256, 0, stream>>>(rel_emb, rel_bf, R * 32); // R*256/8
    }
    fill_kernel<<<(E + 255) / 256, 256, 0, stream>>>(ei, et, deg_src, deg_dst, gate,
                                                     cursor, ids, wbuf, E);
    const int nblk = (N + 31) / 32;
    if (use_bf) {
        fused_kernel<1><<<nblk, 256, 0, stream>>>(out, Kbm, Kbu, h, h_bf, rel_emb, rel_bf,
                                                  offs, deg_dst, ids, wbuf, msg_b, upd_b, N);
    } else {
        fused_kernel<0><<<nblk, 256, 0, stream>>>(out, Kbm, Kbu, h, h_bf, rel_emb, rel_bf,
                                                  offs, deg_dst, ids, wbuf, msg_b, upd_b, N);
    }
}

// Round 4
// 339.103 us; speedup vs baseline: 1.5638x; 1.5638x over previous
//
#include <hip/hip_runtime.h>
#include <math.h>

typedef unsigned int u32;
typedef unsigned short u16;
typedef __attribute__((ext_vector_type(8))) short bf16x8;   // 8 bf16 in 4 VGPRs
typedef __attribute__((ext_vector_type(4))) float f32x4;

__device__ inline u16 f2bf(float x) {  // round-to-nearest-even
    union { float f; u32 u; } v; v.f = x;
    u32 r = v.u + 0x7FFFu + ((v.u >> 16) & 1u);
    return (u16)(r >> 16);
}
__device__ inline float bf2f(u16 x) { return __uint_as_float((u32)x << 16); }
__device__ inline float4 bf4_to_f4(uint2 p) {
    float4 r;
    r.x = __uint_as_float(p.x << 16);
    r.y = __uint_as_float(p.x & 0xffff0000u);
    r.z = __uint_as_float(p.y << 16);
    r.w = __uint_as_float(p.y & 0xffff0000u);
    return r;
}

// ---------------------------------------------------------------------------
// Clifford GNN message passing, restructured:
//   agg[n] = sum_e w_e*(h[src] .* r[rel]),  w_e = gate(rel)*norm(e)
//   t = ML(agg) + h + msg_b*wsum ;  out = UL(t) + upd_b  (channel-major store)
// Split design (round-3 fusion was latency-bound at 37% occupancy):
//   agg_kernel: 1 wave/node, no LDS/barriers -> high occupancy gather;
//               bf16 in (h_bf/rel_bf tables), bf16 out into d_out's row slots
//               (first 512B of each 1KB row slot -> no extra workspace).
//   gemm_kernel: per 32-row block, stage bf16 agg -> swizzled LDS, two MFMA
//               passes, permuted fp32 store overwrites the same row slots.
// ---------------------------------------------------------------------------

// Build Clifford kernel matrices Kb[j][k] = K[j][k] in bf16 (k contiguous).
__global__ void build_mats_kernel(const float* __restrict__ msg_w,
                                  const float* __restrict__ upd_w,
                                  u16* __restrict__ Kbm, u16* __restrict__ Kbu) {
    const int   s_tab[16] = {0,1,2,3, 1,0,3,2, 2,3,0,1, 3,2,1,0};
    const float g_tab[16] = {1.f,1.f,1.f,-1.f, 1.f,1.f,-1.f,1.f,
                             1.f,1.f,1.f,-1.f, 1.f,1.f,1.f,1.f};
    int idx = blockIdx.x * 256 + threadIdx.x;   // idx = j*256 + i
    int j = idx >> 8, i = idx & 255;
    int ob = j >> 6, oc = j & 63, ib = i >> 6, ic = i & 63;
    int t = ob * 4 + ib;
    int widx = s_tab[t] * 4096 + oc * 64 + ic;  // w[s][oc][ic]
    float sg = g_tab[t];
    Kbm[idx] = f2bf(sg * msg_w[widx]);
    Kbu[idx] = f2bf(sg * upd_w[widx]);
}

// gate[r] = sigmoid( sum_j rel_emb[r, j] * gate_w[(j&63)*4 + (j>>6)] + gate_b )
__global__ void gate_kernel(const float* __restrict__ rel_emb,
                            const float* __restrict__ gate_w,
                            const float* __restrict__ gate_b,
                            float* __restrict__ gate, int R) {
    int wv = threadIdx.x >> 6, lane = threadIdx.x & 63;
    int r = blockIdx.x * 4 + wv;
    if (r >= R) return;
    float4 rv = *(const float4*)(rel_emb + (size_t)r * 256 + lane * 4);
    float s = 0.f;
    float rvv[4] = {rv.x, rv.y, rv.z, rv.w};
#pragma unroll
    for (int c = 0; c < 4; ++c) {
        int j = lane * 4 + c;
        s += rvv[c] * gate_w[(j & 63) * 4 + (j >> 6)];
    }
#pragma unroll
    for (int d = 32; d > 0; d >>= 1) s += __shfl_down(s, d);
    if (lane == 0) gate[r] = 1.0f / (1.0f + expf(-(s + gate_b[0])));
}

__global__ void degree_kernel(const int* __restrict__ ei, int E,
                              u32* __restrict__ deg_src, u32* __restrict__ deg_dst) {
    int e = blockIdx.x * 256 + threadIdx.x;
    if (e >= E) return;
    atomicAdd(&deg_src[ei[e]], 1u);
    atomicAdd(&deg_dst[ei[E + e]], 1u);
}

// Parallel bucket allocator (replaces single-block scan: order is irrelevant,
// only disjointness matters). Wave prefix + one atomic per block.
__global__ void alloc_kernel(const u32* __restrict__ deg, u32* __restrict__ offs,
                             u32* __restrict__ cursor, u32* __restrict__ total, int N) {
    __shared__ u32 wt[4];
    __shared__ u32 bbase;
    int tid = threadIdx.x, lane = tid & 63, wv = tid >> 6;
    int i = blockIdx.x * 256 + tid;
    u32 d = (i < N) ? deg[i] : 0u;
    u32 sc = d;
#pragma unroll
    for (int s = 1; s < 64; s <<= 1) { u32 o = __shfl_up(sc, s); if (lane >= s) sc += o; }
    if (lane == 63) wt[wv] = sc;
    __syncthreads();
    if (tid == 0) bbase = atomicAdd(total, wt[0] + wt[1] + wt[2] + wt[3]);
    __syncthreads();
    u32 wpre = 0;
    for (int w = 0; w < wv; ++w) wpre += wt[w];
    u32 off = bbase + wpre + sc - d;
    if (i < N) { offs[i] = off; cursor[i] = off; }
}

// Bucket-fill with precomputed per-edge weight: ids[pos]={src,rel}, wbuf[pos]=w.
__global__ void fill_kernel(const int* __restrict__ ei, const int* __restrict__ et,
                            const u32* __restrict__ deg_src,
                            const u32* __restrict__ deg_dst,
                            const float* __restrict__ gate,
                            u32* __restrict__ cursor,
                            uint2* __restrict__ ids, float* __restrict__ wbuf, int E) {
    int e = blockIdx.x * 256 + threadIdx.x;
    if (e >= E) return;
    int src = ei[e];
    int dst = ei[E + e];
    int rel = et[e];
    float ds = (float)deg_src[src];
    float dd = (float)deg_dst[dst];
    float w = gate[rel] * rsqrtf(fmaxf(ds * dd, 1.0f));
    u32 pos = atomicAdd(&cursor[dst], 1u);
    ids[pos] = make_uint2((u32)src, (u32)rel);
    wbuf[pos] = w;
}

// fp32 -> bf16 bulk convert (8 elems/thread, grid-stride).
__global__ void tobf_kernel(const float* __restrict__ src, u16* __restrict__ dst, int n8) {
    for (int i = blockIdx.x * 256 + threadIdx.x; i < n8; i += gridDim.x * 256) {
        const float* p = src + (size_t)i * 8;
        float4 a = *(const float4*)(p);
        float4 b = *(const float4*)(p + 4);
        u16 tmp[8] = {f2bf(a.x), f2bf(a.y), f2bf(a.z), f2bf(a.w),
                      f2bf(b.x), f2bf(b.y), f2bf(b.z), f2bf(b.w)};
        *(uint4*)(dst + (size_t)i * 8) = *(const uint4*)tmp;
    }
}

// One wave per node, no LDS: agg[n] accumulated fp32, written bf16 into the
// first 512B of d_out's 1KB row slot (agg_bf u16 row stride = 512).
template <int BF>
__global__ __launch_bounds__(256) void agg_kernel(
    const float* __restrict__ h, const u16* __restrict__ h_bf,
    const float* __restrict__ rel_emb, const u16* __restrict__ rel_bf,
    const u32* __restrict__ offs, const u32* __restrict__ deg_dst,
    const uint2* __restrict__ ids, const float* __restrict__ wbuf,
    u16* __restrict__ agg_bf, float* __restrict__ wsum_arr, int N) {
    int wv = threadIdx.x >> 6, lane = threadIdx.x & 63;
    int n = blockIdx.x * 4 + wv;
    if (n >= N) return;
    u32 off = offs[n];
    u32 dd = deg_dst[n];
    float4 acc = make_float4(0.f, 0.f, 0.f, 0.f);
    float wsum = 0.f;
    u32 e = 0;
    for (; e + 2 <= dd; e += 2) {   // 2x unroll for memory-level parallelism
        uint2 id0 = ids[off + e], id1 = ids[off + e + 1];
        float w0 = wbuf[off + e], w1 = wbuf[off + e + 1];
        float4 h0, r0, h1, r1;
        if (BF) {
            h0 = bf4_to_f4(*(const uint2*)(h_bf + (size_t)id0.x * 256 + lane * 4));
            r0 = bf4_to_f4(*(const uint2*)(rel_bf + (size_t)id0.y * 256 + lane * 4));
            h1 = bf4_to_f4(*(const uint2*)(h_bf + (size_t)id1.x * 256 + lane * 4));
            r1 = bf4_to_f4(*(const uint2*)(rel_bf + (size_t)id1.y * 256 + lane * 4));
        } else {
            h0 = *(const float4*)(h + (size_t)id0.x * 256 + lane * 4);
            r0 = *(const float4*)(rel_emb + (size_t)id0.y * 256 + lane * 4);
            h1 = *(const float4*)(h + (size_t)id1.x * 256 + lane * 4);
            r1 = *(const float4*)(rel_emb + (size_t)id1.y * 256 + lane * 4);
        }
        acc.x += w0 * h0.x * r0.x + w1 * h1.x * r1.x;
        acc.y += w0 * h0.y * r0.y + w1 * h1.y * r1.y;
        acc.z += w0 * h0.z * r0.z + w1 * h1.z * r1.z;
        acc.w += w0 * h0.w * r0.w + w1 * h1.w * r1.w;
        wsum += w0 + w1;
    }
    if (e < dd) {
        uint2 id0 = ids[off + e];
        float w0 = wbuf[off + e];
        float4 h0, r0;
        if (BF) {
            h0 = bf4_to_f4(*(const uint2*)(h_bf + (size_t)id0.x * 256 + lane * 4));
            r0 = bf4_to_f4(*(const uint2*)(rel_bf + (size_t)id0.y * 256 + lane * 4));
        } else {
            h0 = *(const float4*)(h + (size_t)id0.x * 256 + lane * 4);
            r0 = *(const float4*)(rel_emb + (size_t)id0.y * 256 + lane * 4);
        }
        acc.x += w0 * h0.x * r0.x;
        acc.y += w0 * h0.y * r0.y;
        acc.z += w0 * h0.z * r0.z;
        acc.w += w0 * h0.w * r0.w;
        wsum += w0;
    }
    u32 lo = (u32)f2bf(acc.x) | ((u32)f2bf(acc.y) << 16);
    u32 hi = (u32)f2bf(acc.z) | ((u32)f2bf(acc.w) << 16);
    *(uint2*)(agg_bf + (size_t)n * 512 + lane * 4) = make_uint2(lo, hi);
    if (lane == 0) wsum_arr[n] = wsum;
}

// Fused double GEMM on MFMA. Per block: 32 rows, 4 waves (each owns 64 cols).
// Stage: bf16 agg rows (d_out slots) -> XOR-swizzled LDS
//        xs index: m*256 + (k ^ ((m&7)<<3)).
// Phase A: t = agg @ Km^T + h + msg_b*wsum (fp32 epilogue, re-round to LDS).
// Phase B: y = t @ Ku^T + upd_b -> permuted channel-major fp32 store (same slots).
template <int BF>
__global__ __launch_bounds__(256) void gemm_kernel(
    float* __restrict__ dio, const u16* __restrict__ agg_bf,
    const u16* __restrict__ Kbm, const u16* __restrict__ Kbu,
    const float* __restrict__ h, const u16* __restrict__ h_bf,
    const float* __restrict__ wsum_arr,
    const float* __restrict__ msg_b, const float* __restrict__ upd_b,
    int N) {
    __shared__ __align__(16) u16 xs[32 * 256];  // 16 KiB bf16 tile
    const int tid = threadIdx.x;
    const int lane = tid & 63;
    const int wv = tid >> 6;        // wave owns output cols [wv*64, wv*64+64)
    const int l15 = lane & 15;
    const int kg = lane >> 4;       // k-group 0..3
    const int m0 = blockIdx.x * 32;
    const int jbase = wv * 64;

    // ---- stage bf16 agg rows -> swizzled LDS (64B per thread) ----
    {
        int m = tid >> 3;                 // 0..31
        int c0 = (tid & 7) * 32;          // col chunk base
        const u16* src = agg_bf + (size_t)(m0 + m) * 512;
        bool ok = (m0 + m) < N;
#pragma unroll
        for (int q = 0; q < 4; ++q) {
            int k = c0 + q * 8;
            uint4 v = make_uint4(0u, 0u, 0u, 0u);
            if (ok) v = *(const uint4*)(src + k);
            *(uint4*)&xs[m * 256 + (k ^ ((m & 7) << 3))] = v;
        }
    }
    __syncthreads();

    f32x4 acc[2][4];

    // ================= phase A: acc = agg @ Km^T =================
#pragma unroll
    for (int mf = 0; mf < 2; ++mf)
#pragma unroll
        for (int nf = 0; nf < 4; ++nf) acc[mf][nf] = (f32x4)(0.f);

#pragma unroll
    for (int k0 = 0; k0 < 256; k0 += 32) {
        int kk = k0 + kg * 8;
        int ma = l15, mb = 16 + l15;
        bf16x8 a0 = *(const bf16x8*)&xs[ma * 256 + (kk ^ ((ma & 7) << 3))];
        bf16x8 a1 = *(const bf16x8*)&xs[mb * 256 + (kk ^ ((mb & 7) << 3))];
#pragma unroll
        for (int nf = 0; nf < 4; ++nf) {
            int j = jbase + nf * 16 + l15;
            bf16x8 b = *(const bf16x8*)(Kbm + (size_t)j * 256 + kk);
            acc[0][nf] = __builtin_amdgcn_mfma_f32_16x16x32_bf16(a0, b, acc[0][nf], 0, 0, 0);
            acc[1][nf] = __builtin_amdgcn_mfma_f32_16x16x32_bf16(a1, b, acc[1][nf], 0, 0, 0);
        }
    }
    __syncthreads();   // all phase-A reads of xs done before overwrite

    // ---- epilogue A: t = acc + h + msg_b*wsum ; t -> bf16 swizzled LDS ----
    float bjA[4];
#pragma unroll
    for (int nf = 0; nf < 4; ++nf) bjA[nf] = msg_b[jbase + nf * 16 + l15];
#pragma unroll
    for (int mf = 0; mf < 2; ++mf) {
#pragma unroll
        for (int r = 0; r < 4; ++r) {
            int m = mf * 16 + kg * 4 + r;             // D-frag row
            int row = m0 + m;
            if (row >= N) continue;
            float ws = wsum_arr[row];
#pragma unroll
            for (int nf = 0; nf < 4; ++nf) {
                int j = jbase + nf * 16 + l15;        // D-frag col
                float hj = BF ? bf2f(h_bf[(size_t)row * 256 + j])
                              : h[(size_t)row * 256 + j];
                float t = acc[mf][nf][r] + hj + bjA[nf] * ws;
                xs[m * 256 + (j ^ ((m & 7) << 3))] = f2bf(t);
            }
        }
    }
    __syncthreads();

    // ================= phase B: acc = t @ Ku^T =================
#pragma unroll
    for (int mf = 0; mf < 2; ++mf)
#pragma unroll
        for (int nf = 0; nf < 4; ++nf) acc[mf][nf] = (f32x4)(0.f);

#pragma unroll
    for (int k0 = 0; k0 < 256; k0 += 32) {
        int kk = k0 + kg * 8;
        int ma = l15, mb = 16 + l15;
        bf16x8 a0 = *(const bf16x8*)&xs[ma * 256 + (kk ^ ((ma & 7) << 3))];
        bf16x8 a1 = *(const bf16x8*)&xs[mb * 256 + (kk ^ ((mb & 7) << 3))];
#pragma unroll
        for (int nf = 0; nf < 4; ++nf) {
            int j = jbase + nf * 16 + l15;
            bf16x8 b = *(const bf16x8*)(Kbu + (size_t)j * 256 + kk);
            acc[0][nf] = __builtin_amdgcn_mfma_f32_16x16x32_bf16(a0, b, acc[0][nf], 0, 0, 0);
            acc[1][nf] = __builtin_amdgcn_mfma_f32_16x16x32_bf16(a1, b, acc[1][nf], 0, 0, 0);
        }
    }

    // ---- epilogue B: y = acc + upd_b[j]; permuted (channel-major) store ----
#pragma unroll
    for (int nf = 0; nf < 4; ++nf) {
        int j = jbase + nf * 16 + l15;
        float bj = upd_b[j];
        int colout = (j & 63) * 4 + wv;               // j>>6 == wv for this wave
#pragma unroll
        for (int mf = 0; mf < 2; ++mf) {
#pragma unroll
            for (int r = 0; r < 4; ++r) {
                int row = m0 + mf * 16 + kg * 4 + r;
                if (row < N) dio[(size_t)row * 256 + colout] = acc[mf][nf][r] + bj;
            }
        }
    }
}

static inline size_t align4(size_t x) { return (x + 3) & ~(size_t)3; }

extern "C" void kernel_launch(void* const* d_in, const int* in_sizes, int n_in,
                              void* d_out, int out_size, void* d_ws, size_t ws_size,
                              hipStream_t stream) {
    const float* h       = (const float*)d_in[0];
    const int*   ei      = (const int*)d_in[1];   // (2,E) row-major
    const int*   et      = (const int*)d_in[2];
    const float* rel_emb = (const float*)d_in[3];
    const float* msg_w   = (const float*)d_in[4];
    const float* msg_b   = (const float*)d_in[5];
    const float* upd_w   = (const float*)d_in[6];
    const float* upd_b   = (const float*)d_in[7];
    const float* gate_w  = (const float*)d_in[8];
    const float* gate_b  = (const float*)d_in[9];

    const int N = in_sizes[0] / 256;
    const int E = in_sizes[2];
    const int R = in_sizes[3] / 256;

    // workspace layout (u32 units); total+deg_src+deg_dst contiguous for memset
    u32* ws = (u32*)d_ws;
    size_t o = 0;
    u32* total    = ws + o; o += 4;
    u32* deg_src  = ws + o; o += align4((size_t)N);
    u32* deg_dst  = ws + o; o += align4((size_t)N);
    u32* offs     = ws + o; o += align4((size_t)N);
    u32* cursor   = ws + o; o += align4((size_t)N);
    float* wsum   = (float*)(ws + o); o += align4((size_t)N);
    float* gate   = (float*)(ws + o); o += align4((size_t)R);
    uint2* ids    = (uint2*)(ws + o); o += (size_t)2 * E;
    float* wbuf   = (float*)(ws + o); o += align4((size_t)E);
    u16* Kbm      = (u16*)(ws + o); o += 32768;  // 256*256 bf16
    u16* Kbu      = (u16*)(ws + o); o += 32768;
    size_t need_base = o;
    u16* h_bf     = (u16*)(ws + o); o += (size_t)N * 128;
    u16* rel_bf   = (u16*)(ws + o); o += (size_t)R * 128;
    size_t need_bf = o;

    if (ws_size < need_base * 4) return;  // insufficient scratch -> fail loudly
    const bool use_bf = (ws_size >= need_bf * 4);

    float* out = (float*)d_out;
    u16* agg_bf = (u16*)d_out;   // bf16 rows at u16 stride 512 (half of each slot)

    // zero total + degree counters (contiguous)
    hipMemsetAsync(total, 0, (4 + 2 * align4((size_t)N)) * 4, stream);

    build_mats_kernel<<<256, 256, 0, stream>>>(msg_w, upd_w, Kbm, Kbu);
    gate_kernel<<<(R + 3) / 4, 256, 0, stream>>>(rel_emb, gate_w, gate_b, gate, R);
    degree_kernel<<<(E + 255) / 256, 256, 0, stream>>>(ei, E, deg_src, deg_dst);
    alloc_kernel<<<(N + 255) / 256, 256, 0, stream>>>(deg_dst, offs, cursor, total, N);
    if (use_bf) {
        tobf_kernel<<<1024, 256, 0, stream>>>(h, h_bf, N * 32);       // N*256/8
        tobf_kernel<<<64, 256, 0, stream>>>(rel_emb, rel_bf, R * 32); // R*256/8
    }
    fill_kernel<<<(E + 255) / 256, 256, 0, stream>>>(ei, et, deg_src, deg_dst, gate,
                                                     cursor, ids, wbuf, E);
    const int nblk = (N + 31) / 32;
    if (use_bf) {
        agg_kernel<1><<<(N + 3) / 4, 256, 0, stream>>>(h, h_bf, rel_emb, rel_bf, offs,
                                                       deg_dst, ids, wbuf, agg_bf, wsum, N);
        gemm_kernel<1><<<nblk, 256, 0, stream>>>(out, agg_bf, Kbm, Kbu, h, h_bf,
                                                 wsum, msg_b, upd_b, N);
    } else {
        agg_kernel<0><<<(N + 3) / 4, 256, 0, stream>>>(h, h_bf, rel_emb, rel_bf, offs,
                                                       deg_dst, ids, wbuf, agg_bf, wsum, N);
        gemm_kernel<0><<<nblk, 256, 0, stream>>>(out, agg_bf, Kbm, Kbu, h, h_bf,
                                                 wsum, msg_b, upd_b, N);
    }
}